// Round 10
// baseline (210.906 us; speedup 1.0000x reference)
//
#include <hip/hip_runtime.h>
#include <math.h>

// GCN 2-layer, N=100K, E=3.2M, feat 1->16->2, log_softmax.
//
// R9 lesson (rocprof): with nb=391 buckets, place's scattered 8B stores hit
// ~60 distinct lines per wave instruction -> store-issue bound (54us at
// 1.3TB/s, occupancy 18%). Everything bad scales with bucket count.
// R10: CHUNK=4096 -> nb=25 buckets. place does an LDS permutation sort
// (u32 perm = k<<12 | dstLow, 48KB) and writes the payload FULLY COALESCED
// in tile order (amplification 1.0); runs are ~492 edges so aggregation
// assigns one block per (bucket, 1/24 slice of tiles): reads 2 rowOff words
// per tile, streams the run coalesced into LDS acc[4096], writes a 16KB
// partial; a merge kernel reduces K=24 partials + per-node epilogue.
// No global float atomics, no per-edge metadata, no hist/scan pre-kernels.
// Algebra: layer1 rank-1 (scalar s per node); 2-class log_softmax needs only
// d = a1-a0 (scalar gd per node); dinv[dst] factored into epilogues.

static constexpr int EPT    = 12288;  // edges per place tile
static constexpr int BS_P   = 512;    // place threads
static constexpr int DREG   = EPT / BS_P;   // 24 dst regs per thread
static constexpr int CHUNK  = 4096;   // nodes per bucket (pow2)
static constexpr int LOGC   = 12;
static constexpr int MAXNB  = 32;     // nb cap (N <= 131072)
static constexpr int HREP   = 16;     // hist replicas
static constexpr int K      = 24;     // tile slices per bucket
static constexpr int BSA    = 512;    // agg part threads
static constexpr int BSM    = 256;    // merge threads

// ======================= place: LDS perm sort + coalesced write =======================

__global__ __launch_bounds__(BS_P) void place_kernel(
    const int* __restrict__ src, const int* __restrict__ dst,
    const float* __restrict__ w,
    unsigned int* __restrict__ rowOff,          // [nT][nb+1]
    unsigned long long* __restrict__ payload,   // [E] tile-ordered, bucket-sorted within tile
    int E, int nb) {
    __shared__ unsigned int perm[EPT];          // 48 KB: k<<LOGC | dstLow
    __shared__ unsigned int h[HREP * 33];       // replicated hist, stride 33 (bank spread)
    __shared__ unsigned int cur[MAXNB + 1];
    __shared__ unsigned int off[MAXNB + 1];
    const int tile = blockIdx.x;
    const int base = tile * EPT;
    const int nE   = min(EPT, E - base);
    const int t    = threadIdx.x;

    for (int i = t; i < HREP * 33; i += BS_P) h[i] = 0u;
    __syncthreads();

    int dreg[DREG];
    {
        int c = 0;
        for (int k = t; k < nE; k += BS_P) {
            int d = dst[base + k];
            dreg[c++] = d;
            atomicAdd(&h[(t & (HREP - 1)) * 33 + ((unsigned int)d >> LOGC)], 1u);
        }
    }
    __syncthreads();
    if (t < nb) {                                // reduce replicas
        unsigned int s = 0;
#pragma unroll
        for (int r = 0; r < HREP; ++r) s += h[r * 33 + t];
        cur[t] = s;
    }
    __syncthreads();
    if (t == 0) {                                // tiny serial exclusive scan
        unsigned int run = 0;
        for (int b = 0; b < nb; ++b) {
            unsigned int c = cur[b];
            off[b] = run; cur[b] = run; run += c;
        }
        off[nb] = run;                           // == nE
    }
    __syncthreads();
    if (t <= nb) rowOff[(size_t)tile * (nb + 1) + t] = off[t];
    {
        int c = 0;
        for (int k = t; k < nE; k += BS_P) {
            int d = dreg[c++];
            unsigned int slot = atomicAdd(&cur[(unsigned int)d >> LOGC], 1u);
            perm[slot] = ((unsigned int)k << LOGC) | (unsigned int)(d & (CHUNK - 1));
        }
    }
    __syncthreads();
    // coalesced write-out; src/w gathers stay in the tile's L2-hot 48 KB windows
    for (int k = t; k < nE; k += BS_P) {
        unsigned int pe = perm[k];
        int j = (int)(pe >> LOGC);
        unsigned int sv = (unsigned int)src[base + j];
        float wv = w[base + j];
        payload[(size_t)base + k] =
            ((unsigned long long)__float_as_uint(wv) << 32) |
            (sv << LOGC) | (pe & (CHUNK - 1));
    }
}

// ======================= aggregation: part + merge =======================

__global__ __launch_bounds__(BSA) void deg_part_kernel(
    const unsigned long long* __restrict__ payload,
    const unsigned int* __restrict__ rowOff,
    float* __restrict__ partial,     // [nb*K][CHUNK]
    int E, int nb, int nT) {
    __shared__ float acc[CHUNK];
    const int b = blockIdx.x / K, k = blockIdx.x % K;
    const int t = threadIdx.x;
    for (int i = t; i < CHUNK; i += BSA) acc[i] = 0.0f;
    __syncthreads();
    for (int tile = k; tile < nT; tile += K) {
        unsigned int o0 = rowOff[(size_t)tile * (nb + 1) + b];
        unsigned int o1 = rowOff[(size_t)tile * (nb + 1) + b + 1];
        const unsigned long long* p = payload + (size_t)tile * EPT;
        for (unsigned int i = o0 + t; i < o1; i += BSA) {
            unsigned long long pv = p[i];
            atomicAdd(&acc[(unsigned int)pv & (CHUNK - 1)],
                      __uint_as_float((unsigned int)(pv >> 32)));
        }
    }
    __syncthreads();
    float* dp = partial + (size_t)blockIdx.x * CHUNK;
    for (int i = t; i < CHUNK; i += BSA) dp[i] = acc[i];
}

__global__ __launch_bounds__(BSM) void deg_merge_kernel(
    const float* __restrict__ partial,
    const float* __restrict__ x,
    float* __restrict__ dinv, float* __restrict__ xd, int N) {
    int n = blockIdx.x * BSM + threadIdx.x;
    if (n >= N) return;
    int b = n >> LOGC, lo = n & (CHUNK - 1);
    const float* pp = partial + ((size_t)b * K) * CHUNK + lo;
    float s = 0.0f;
#pragma unroll
    for (int k = 0; k < K; ++k) s += pp[(size_t)k * CHUNK];
    float d = s + 1.0f;                          // self-loop fill 1.0
    float r = (d > 0.0f) ? rsqrtf(d) : 0.0f;
    dinv[n] = r;
    xd[n]   = r * x[n];
}

__global__ __launch_bounds__(BSA) void s_part_kernel(
    const unsigned long long* __restrict__ payload,
    const unsigned int* __restrict__ rowOff,
    const float* __restrict__ xd,
    float* __restrict__ partial, int E, int nb, int nT) {
    __shared__ float acc[CHUNK];
    const int b = blockIdx.x / K, k = blockIdx.x % K;
    const int t = threadIdx.x;
    for (int i = t; i < CHUNK; i += BSA) acc[i] = 0.0f;
    __syncthreads();
    for (int tile = k; tile < nT; tile += K) {
        unsigned int o0 = rowOff[(size_t)tile * (nb + 1) + b];
        unsigned int o1 = rowOff[(size_t)tile * (nb + 1) + b + 1];
        const unsigned long long* p = payload + (size_t)tile * EPT;
        for (unsigned int i = o0 + t; i < o1; i += BSA) {
            unsigned long long pv = p[i];
            unsigned int lo32 = (unsigned int)pv;
            float xv = xd[(lo32 >> LOGC) & 0x1FFFFu];
            atomicAdd(&acc[lo32 & (CHUNK - 1)],
                      __uint_as_float((unsigned int)(pv >> 32)) * xv);
        }
    }
    __syncthreads();
    float* dp = partial + (size_t)blockIdx.x * CHUNK;
    for (int i = t; i < CHUNK; i += BSA) dp[i] = acc[i];
}

__global__ __launch_bounds__(BSM) void s_merge_kernel(
    const float* __restrict__ partial,
    const float* __restrict__ dinv,
    const float* __restrict__ xd,
    const float* __restrict__ W1,    // [16]
    const float* __restrict__ b1,    // [16]
    const float* __restrict__ W2,    // [16][2]
    float* __restrict__ gd, int N) {
    int n = blockIdx.x * BSM + threadIdx.x;
    if (n >= N) return;
    int b = n >> LOGC, lo = n & (CHUNK - 1);
    const float* pp = partial + ((size_t)b * K) * CHUNK + lo;
    float s = 0.0f;
#pragma unroll
    for (int k = 0; k < K; ++k) s += pp[(size_t)k * CHUNK];
    float dv = dinv[n];
    float sv = dv * (s + xd[n]);                 // + self-loop dv*dv*x[n]
    float g = 0.0f;
#pragma unroll
    for (int f = 0; f < 16; ++f) {
        float h = fmaxf(sv * W1[f] + b1[f], 0.0f);        // relu(layer1)
        g += h * (W2[2 * f + 1] - W2[2 * f + 0]);         // gamma = g1-g0
    }
    gd[n] = dv * g;                              // pre-scaled for layer 2
}

__global__ __launch_bounds__(BSA) void d_part_kernel(
    const unsigned long long* __restrict__ payload,
    const unsigned int* __restrict__ rowOff,
    const float* __restrict__ gd,
    float* __restrict__ partial, int E, int nb, int nT) {
    __shared__ float acc[CHUNK];
    const int b = blockIdx.x / K, k = blockIdx.x % K;
    const int t = threadIdx.x;
    for (int i = t; i < CHUNK; i += BSA) acc[i] = 0.0f;
    __syncthreads();
    for (int tile = k; tile < nT; tile += K) {
        unsigned int o0 = rowOff[(size_t)tile * (nb + 1) + b];
        unsigned int o1 = rowOff[(size_t)tile * (nb + 1) + b + 1];
        const unsigned long long* p = payload + (size_t)tile * EPT;
        for (unsigned int i = o0 + t; i < o1; i += BSA) {
            unsigned long long pv = p[i];
            unsigned int lo32 = (unsigned int)pv;
            float gv = gd[(lo32 >> LOGC) & 0x1FFFFu];
            atomicAdd(&acc[lo32 & (CHUNK - 1)],
                      __uint_as_float((unsigned int)(pv >> 32)) * gv);
        }
    }
    __syncthreads();
    float* dp = partial + (size_t)blockIdx.x * CHUNK;
    for (int i = t; i < CHUNK; i += BSA) dp[i] = acc[i];
}

__global__ __launch_bounds__(BSM) void d_merge_kernel(
    const float* __restrict__ partial,
    const float* __restrict__ dinv,
    const float* __restrict__ gd,
    const float* __restrict__ b2,    // [2]
    float* __restrict__ out, int N) {
    int n = blockIdx.x * BSM + threadIdx.x;
    if (n >= N) return;
    int b = n >> LOGC, lo = n & (CHUNK - 1);
    const float* pp = partial + ((size_t)b * K) * CHUNK + lo;
    float s = 0.0f;
#pragma unroll
    for (int k = 0; k < K; ++k) s += pp[(size_t)k * CHUNK];
    float dv = dinv[n];
    float d = dv * (s + gd[n]) + (b2[1] - b2[0]);
    float lse = fmaxf(d, 0.0f) + log1pf(expf(-fabsf(d)));   // log(1+e^d), stable
    out[2 * n + 0] = -lse;
    out[2 * n + 1] = d - lse;
}

// ======================= fallback: R3 global-atomic path =======================

static constexpr int BLOCK = 256;

__global__ void zero_kernel(float* __restrict__ a, float* __restrict__ b, int n2) {
    int i = blockIdx.x * blockDim.x + threadIdx.x;
    if (i < n2) { a[i] = 0.0f; b[i] = 0.0f; }
}
__global__ void deg_kernel(const int* __restrict__ dst, const float* __restrict__ w,
                           float* __restrict__ deg, int E) {
    int e = blockIdx.x * blockDim.x + threadIdx.x;
    if (e < E) atomicAdd(&deg[dst[e]], w[e]);
}
__global__ void dinv_kernel(float* __restrict__ deg, int N) {
    int n = blockIdx.x * blockDim.x + threadIdx.x;
    if (n < N) {
        float d = deg[n] + 1.0f;
        deg[n] = (d > 0.0f) ? rsqrtf(d) : 0.0f;
    }
}
__global__ void s_kernel(const int* __restrict__ src, const int* __restrict__ dst,
                         const float* __restrict__ w, const float* __restrict__ dinv,
                         const float* __restrict__ x, float* __restrict__ s, int E) {
    int e = blockIdx.x * blockDim.x + threadIdx.x;
    if (e < E) {
        int si = src[e], di = dst[e];
        atomicAdd(&s[di], dinv[si] * w[e] * dinv[di] * x[si]);
    }
}
__global__ void g_kernel(const float* __restrict__ s, const float* __restrict__ dinv,
                         const float* __restrict__ x, const float* __restrict__ W1,
                         const float* __restrict__ b1, const float* __restrict__ W2,
                         float2* __restrict__ g, int N) {
    int n = blockIdx.x * blockDim.x + threadIdx.x;
    if (n < N) {
        float dv = dinv[n];
        float sv = s[n] + dv * dv * x[n];
        float g0 = 0.0f, g1 = 0.0f;
#pragma unroll
        for (int f = 0; f < 16; ++f) {
            float h = fmaxf(sv * W1[f] + b1[f], 0.0f);
            g0 += h * W2[2 * f + 0];
            g1 += h * W2[2 * f + 1];
        }
        g[n] = make_float2(g0, g1);
    }
}
__global__ void agg2_kernel(const int* __restrict__ src, const int* __restrict__ dst,
                            const float* __restrict__ w, const float* __restrict__ dinv,
                            const float2* __restrict__ g, float* __restrict__ agg, int E) {
    int e = blockIdx.x * blockDim.x + threadIdx.x;
    if (e < E) {
        int si = src[e], di = dst[e];
        float norm = dinv[si] * w[e] * dinv[di];
        float2 gv = g[si];
        atomicAdd(&agg[2 * di + 0], norm * gv.x);
        atomicAdd(&agg[2 * di + 1], norm * gv.y);
    }
}
__global__ void out_kernel(float* __restrict__ out, const float* __restrict__ dinv,
                           const float2* __restrict__ g, const float* __restrict__ b2, int N) {
    int n = blockIdx.x * blockDim.x + threadIdx.x;
    if (n < N) {
        float dv2 = dinv[n] * dinv[n];
        float2 gv = g[n];
        float a0 = out[2 * n + 0] + dv2 * gv.x + b2[0];
        float a1 = out[2 * n + 1] + dv2 * gv.y + b2[1];
        float m = fmaxf(a0, a1);
        float lse = m + logf(expf(a0 - m) + expf(a1 - m));
        out[2 * n + 0] = a0 - lse;
        out[2 * n + 1] = a1 - lse;
    }
}

// ======================= launch =======================

extern "C" void kernel_launch(void* const* d_in, const int* in_sizes, int n_in,
                              void* d_out, int out_size, void* d_ws, size_t ws_size,
                              hipStream_t stream) {
    const float* x  = (const float*)d_in[0];
    const int*   ei = (const int*)d_in[1];     // [2, E] delivered as int32
    const float* w  = (const float*)d_in[2];
    const float* W1 = (const float*)d_in[3];
    const float* b1 = (const float*)d_in[4];
    const float* W2 = (const float*)d_in[5];
    const float* b2 = (const float*)d_in[6];
    float* out = (float*)d_out;

    const int N = in_sizes[0];
    const int E = in_sizes[2];
    const int* src = ei;
    const int* dst = ei + E;

    const int nb = (N + CHUNK - 1) / CHUNK;    // 25
    const int nT = (E + EPT - 1) / EPT;        // 261

    // ws layout: payload | rowOff | partial | dinv | xd | gd
    size_t off = 0;
    size_t payload_off = off;  off += (size_t)nT * EPT * 8;
    size_t rowoff_off  = off;  off += (size_t)nT * (nb + 1) * 4;
    off = (off + 7) & ~(size_t)7;
    size_t partial_off = off;  off += (size_t)nb * K * CHUNK * 4;
    size_t dinv_off    = off;  off += (size_t)N * 4;
    size_t xd_off      = off;  off += (size_t)N * 4;
    size_t gd_off      = off;  off += (size_t)N * 4;
    const size_t required = off;

    if (nb <= MAXNB && N <= 131072 && ws_size >= required) {
        char* wsb = (char*)d_ws;
        unsigned long long* payload = (unsigned long long*)(wsb + payload_off);
        unsigned int* rowOff = (unsigned int*)(wsb + rowoff_off);
        float* partial = (float*)(wsb + partial_off);
        float* dinv = (float*)(wsb + dinv_off);
        float* xd   = (float*)(wsb + xd_off);
        float* gd   = (float*)(wsb + gd_off);

        const int gridM = (N + BSM - 1) / BSM;

        place_kernel    <<<nT,     BS_P, 0, stream>>>(src, dst, w, rowOff, payload, E, nb);
        deg_part_kernel <<<nb * K, BSA,  0, stream>>>(payload, rowOff, partial, E, nb, nT);
        deg_merge_kernel<<<gridM,  BSM,  0, stream>>>(partial, x, dinv, xd, N);
        s_part_kernel   <<<nb * K, BSA,  0, stream>>>(payload, rowOff, xd, partial, E, nb, nT);
        s_merge_kernel  <<<gridM,  BSM,  0, stream>>>(partial, dinv, xd, W1, b1, W2, gd, N);
        d_part_kernel   <<<nb * K, BSA,  0, stream>>>(payload, rowOff, gd, partial, E, nb, nT);
        d_merge_kernel  <<<gridM,  BSM,  0, stream>>>(partial, dinv, gd, b2, out, N);
    } else {
        // R3 fallback: global-atomic path (needs 4N floats of ws)
        float*  ws   = (float*)d_ws;
        float*  dinv = ws;
        float*  s    = ws + (size_t)N;
        float2* g    = (float2*)(ws + (size_t)2 * N);
        const int gridE  = (E + BLOCK - 1) / BLOCK;
        const int gridN  = (N + BLOCK - 1) / BLOCK;
        const int gridN2 = (2 * N + BLOCK - 1) / BLOCK;
        zero_kernel<<<gridN2, BLOCK, 0, stream>>>(ws, out, 2 * N);
        deg_kernel <<<gridE,  BLOCK, 0, stream>>>(dst, w, dinv, E);
        dinv_kernel<<<gridN,  BLOCK, 0, stream>>>(dinv, N);
        s_kernel   <<<gridE,  BLOCK, 0, stream>>>(src, dst, w, dinv, x, s, E);
        g_kernel   <<<gridN,  BLOCK, 0, stream>>>(s, dinv, x, W1, b1, W2, g, N);
        agg2_kernel<<<gridE,  BLOCK, 0, stream>>>(src, dst, w, dinv, g, out, E);
        out_kernel <<<gridN,  BLOCK, 0, stream>>>(out, dinv, g, b2, N);
    }
}

// Round 11
// 207.394 us; speedup vs baseline: 1.0169x; 1.0169x over previous
//
#include <hip/hip_runtime.h>
#include <math.h>

// GCN 2-layer, N=100K, E=3.2M, feat 1->16->2, log_softmax.
//
// R10 lesson (rocprof): WRITE amplification is solved (25 MB, coalesced
// perm-sort write-out) but EPT=12288 -> 48KB LDS -> grid 261 ~= 1 block/CU,
// occupancy 14%, place latency-bound at 900 GB/s. Grids must stay >= ~780.
// R11: CHUNK=8192 (nb=13, runs ~315 edges = 2.5KB, amp ~1.03);
//   place: EPT=4096 @ BS=256 (perm 16KB) -> 782 blocks, ~3 blocks/CU;
//   agg:   block=(bucket, slice), K=60 -> 780 blocks, acc[8192]=32KB,
//          runs 315 >= 256 threads -> good utilization; partial+merge.
// No global float atomics. Payload u64 = w<<32 | src<<13 | dstLow(13b).
// Algebra: layer1 rank-1 (scalar s per node); 2-class log_softmax needs only
// d = a1-a0 (scalar gd per node); dinv[dst] factored into epilogues.

static constexpr int EPT   = 4096;   // edges per place tile
static constexpr int BS_P  = 256;    // place threads
static constexpr int DREG  = EPT / BS_P;   // 16
static constexpr int CHUNK = 8192;   // nodes per bucket (pow2)
static constexpr int LOGC  = 13;
static constexpr int NBMAX = 16;
static constexpr int HREP  = 8;      // hist replicas
static constexpr int HSTR  = 17;     // replica stride (bank spread)
static constexpr int K     = 60;     // tile slices per bucket
static constexpr int BSA   = 256;    // agg part threads
static constexpr int BSM   = 256;    // merge threads

// ======================= place: LDS perm sort + coalesced write =======================

__global__ __launch_bounds__(BS_P) void place_kernel(
    const int* __restrict__ src, const int* __restrict__ dst,
    const float* __restrict__ w,
    unsigned int* __restrict__ rowOff,          // [nT][nb+1]
    unsigned long long* __restrict__ payload,   // [E] tile-ordered, bucket-sorted in tile
    int E, int nb) {
    __shared__ unsigned int perm[EPT];          // 16 KB: k<<13 | dstLow
    __shared__ unsigned int h[HREP * HSTR];
    __shared__ unsigned int cur[NBMAX + 1];
    __shared__ unsigned int off[NBMAX + 1];
    const int tile = blockIdx.x;
    const int base = tile * EPT;
    const int nE   = min(EPT, E - base);
    const int t    = threadIdx.x;

    for (int i = t; i < HREP * HSTR; i += BS_P) h[i] = 0u;
    __syncthreads();

    int dreg[DREG];
    {
        int c = 0;
        for (int k = t; k < nE; k += BS_P) {
            int d = dst[base + k];
            dreg[c++] = d;
            atomicAdd(&h[(t & (HREP - 1)) * HSTR + ((unsigned int)d >> LOGC)], 1u);
        }
    }
    __syncthreads();
    if (t < nb) {
        unsigned int s = 0;
#pragma unroll
        for (int r = 0; r < HREP; ++r) s += h[r * HSTR + t];
        cur[t] = s;
    }
    __syncthreads();
    if (t == 0) {                                // tiny serial exclusive scan (nb<=16)
        unsigned int run = 0;
        for (int b = 0; b < nb; ++b) {
            unsigned int c = cur[b];
            off[b] = run; cur[b] = run; run += c;
        }
        off[nb] = run;                           // == nE
    }
    __syncthreads();
    if (t <= nb) rowOff[(size_t)tile * (nb + 1) + t] = off[t];
    {
        int c = 0;
        for (int k = t; k < nE; k += BS_P) {
            int d = dreg[c++];
            unsigned int slot = atomicAdd(&cur[(unsigned int)d >> LOGC], 1u);
            perm[slot] = ((unsigned int)k << LOGC) | (unsigned int)(d & (CHUNK - 1));
        }
    }
    __syncthreads();
    // coalesced write-out; src/w gathers stay within the tile's 16 KB windows
    for (int k = t; k < nE; k += BS_P) {
        unsigned int pe = perm[k];
        int j = (int)(pe >> LOGC);
        unsigned int sv = (unsigned int)src[base + j];
        float wv = w[base + j];
        payload[(size_t)base + k] =
            ((unsigned long long)__float_as_uint(wv) << 32) |
            (sv << LOGC) | (pe & (CHUNK - 1));
    }
}

// ======================= aggregation: part + merge =======================

__global__ __launch_bounds__(BSA) void deg_part_kernel(
    const unsigned long long* __restrict__ payload,
    const unsigned int* __restrict__ rowOff,
    float* __restrict__ partial,     // [nb*K][CHUNK]
    int nb, int nT) {
    __shared__ float acc[CHUNK];
    const int b = blockIdx.x % nb, k = blockIdx.x / nb;
    const int t = threadIdx.x;
    for (int i = t; i < CHUNK; i += BSA) acc[i] = 0.0f;
    __syncthreads();
    const int T0 = (nT + K - 1) / K;
    const int t0 = k * T0, t1 = min(t0 + T0, nT);
    for (int tile = t0; tile < t1; ++tile) {
        unsigned int o0 = rowOff[(size_t)tile * (nb + 1) + b];
        unsigned int o1 = rowOff[(size_t)tile * (nb + 1) + b + 1];
        const unsigned long long* p = payload + (size_t)tile * EPT;
        for (unsigned int i = o0 + t; i < o1; i += BSA) {
            unsigned long long pv = p[i];
            atomicAdd(&acc[(unsigned int)pv & (CHUNK - 1)],
                      __uint_as_float((unsigned int)(pv >> 32)));
        }
    }
    __syncthreads();
    float* dp = partial + (size_t)(b * K + k) * CHUNK;
    for (int i = t; i < CHUNK; i += BSA) dp[i] = acc[i];
}

__global__ __launch_bounds__(BSM) void deg_merge_kernel(
    const float* __restrict__ partial,
    const float* __restrict__ x,
    float* __restrict__ dinv, float* __restrict__ xd, int N) {
    int n = blockIdx.x * BSM + threadIdx.x;
    if (n >= N) return;
    int b = n >> LOGC, lo = n & (CHUNK - 1);
    const float* pp = partial + ((size_t)b * K) * CHUNK + lo;
    float s = 0.0f;
#pragma unroll
    for (int k = 0; k < K; ++k) s += pp[(size_t)k * CHUNK];
    float d = s + 1.0f;                          // self-loop fill 1.0
    float r = (d > 0.0f) ? rsqrtf(d) : 0.0f;
    dinv[n] = r;
    xd[n]   = r * x[n];
}

__global__ __launch_bounds__(BSA) void s_part_kernel(
    const unsigned long long* __restrict__ payload,
    const unsigned int* __restrict__ rowOff,
    const float* __restrict__ xd,
    float* __restrict__ partial, int nb, int nT) {
    __shared__ float acc[CHUNK];
    const int b = blockIdx.x % nb, k = blockIdx.x / nb;
    const int t = threadIdx.x;
    for (int i = t; i < CHUNK; i += BSA) acc[i] = 0.0f;
    __syncthreads();
    const int T0 = (nT + K - 1) / K;
    const int t0 = k * T0, t1 = min(t0 + T0, nT);
    for (int tile = t0; tile < t1; ++tile) {
        unsigned int o0 = rowOff[(size_t)tile * (nb + 1) + b];
        unsigned int o1 = rowOff[(size_t)tile * (nb + 1) + b + 1];
        const unsigned long long* p = payload + (size_t)tile * EPT;
        for (unsigned int i = o0 + t; i < o1; i += BSA) {
            unsigned long long pv = p[i];
            unsigned int lo32 = (unsigned int)pv;
            float xv = xd[lo32 >> LOGC];
            atomicAdd(&acc[lo32 & (CHUNK - 1)],
                      __uint_as_float((unsigned int)(pv >> 32)) * xv);
        }
    }
    __syncthreads();
    float* dp = partial + (size_t)(b * K + k) * CHUNK;
    for (int i = t; i < CHUNK; i += BSA) dp[i] = acc[i];
}

__global__ __launch_bounds__(BSM) void s_merge_kernel(
    const float* __restrict__ partial,
    const float* __restrict__ dinv,
    const float* __restrict__ xd,
    const float* __restrict__ W1,    // [16]
    const float* __restrict__ b1,    // [16]
    const float* __restrict__ W2,    // [16][2]
    float* __restrict__ gd, int N) {
    int n = blockIdx.x * BSM + threadIdx.x;
    if (n >= N) return;
    int b = n >> LOGC, lo = n & (CHUNK - 1);
    const float* pp = partial + ((size_t)b * K) * CHUNK + lo;
    float s = 0.0f;
#pragma unroll
    for (int k = 0; k < K; ++k) s += pp[(size_t)k * CHUNK];
    float dv = dinv[n];
    float sv = dv * (s + xd[n]);                 // + self-loop dv*dv*x[n]
    float g = 0.0f;
#pragma unroll
    for (int f = 0; f < 16; ++f) {
        float h = fmaxf(sv * W1[f] + b1[f], 0.0f);        // relu(layer1)
        g += h * (W2[2 * f + 1] - W2[2 * f + 0]);         // gamma = g1-g0
    }
    gd[n] = dv * g;                              // pre-scaled for layer 2
}

__global__ __launch_bounds__(BSA) void d_part_kernel(
    const unsigned long long* __restrict__ payload,
    const unsigned int* __restrict__ rowOff,
    const float* __restrict__ gd,
    float* __restrict__ partial, int nb, int nT) {
    __shared__ float acc[CHUNK];
    const int b = blockIdx.x % nb, k = blockIdx.x / nb;
    const int t = threadIdx.x;
    for (int i = t; i < CHUNK; i += BSA) acc[i] = 0.0f;
    __syncthreads();
    const int T0 = (nT + K - 1) / K;
    const int t0 = k * T0, t1 = min(t0 + T0, nT);
    for (int tile = t0; tile < t1; ++tile) {
        unsigned int o0 = rowOff[(size_t)tile * (nb + 1) + b];
        unsigned int o1 = rowOff[(size_t)tile * (nb + 1) + b + 1];
        const unsigned long long* p = payload + (size_t)tile * EPT;
        for (unsigned int i = o0 + t; i < o1; i += BSA) {
            unsigned long long pv = p[i];
            unsigned int lo32 = (unsigned int)pv;
            float gv = gd[lo32 >> LOGC];
            atomicAdd(&acc[lo32 & (CHUNK - 1)],
                      __uint_as_float((unsigned int)(pv >> 32)) * gv);
        }
    }
    __syncthreads();
    float* dp = partial + (size_t)(b * K + k) * CHUNK;
    for (int i = t; i < CHUNK; i += BSA) dp[i] = acc[i];
}

__global__ __launch_bounds__(BSM) void d_merge_kernel(
    const float* __restrict__ partial,
    const float* __restrict__ dinv,
    const float* __restrict__ gd,
    const float* __restrict__ b2,    // [2]
    float* __restrict__ out, int N) {
    int n = blockIdx.x * BSM + threadIdx.x;
    if (n >= N) return;
    int b = n >> LOGC, lo = n & (CHUNK - 1);
    const float* pp = partial + ((size_t)b * K) * CHUNK + lo;
    float s = 0.0f;
#pragma unroll
    for (int k = 0; k < K; ++k) s += pp[(size_t)k * CHUNK];
    float dv = dinv[n];
    float d = dv * (s + gd[n]) + (b2[1] - b2[0]);
    float lse = fmaxf(d, 0.0f) + log1pf(expf(-fabsf(d)));   // log(1+e^d), stable
    out[2 * n + 0] = -lse;
    out[2 * n + 1] = d - lse;
}

// ======================= fallback: R3 global-atomic path =======================

static constexpr int BLOCK = 256;

__global__ void zero_kernel(float* __restrict__ a, float* __restrict__ b, int n2) {
    int i = blockIdx.x * blockDim.x + threadIdx.x;
    if (i < n2) { a[i] = 0.0f; b[i] = 0.0f; }
}
__global__ void deg_kernel(const int* __restrict__ dst, const float* __restrict__ w,
                           float* __restrict__ deg, int E) {
    int e = blockIdx.x * blockDim.x + threadIdx.x;
    if (e < E) atomicAdd(&deg[dst[e]], w[e]);
}
__global__ void dinv_kernel(float* __restrict__ deg, int N) {
    int n = blockIdx.x * blockDim.x + threadIdx.x;
    if (n < N) {
        float d = deg[n] + 1.0f;
        deg[n] = (d > 0.0f) ? rsqrtf(d) : 0.0f;
    }
}
__global__ void s_kernel(const int* __restrict__ src, const int* __restrict__ dst,
                         const float* __restrict__ w, const float* __restrict__ dinv,
                         const float* __restrict__ x, float* __restrict__ s, int E) {
    int e = blockIdx.x * blockDim.x + threadIdx.x;
    if (e < E) {
        int si = src[e], di = dst[e];
        atomicAdd(&s[di], dinv[si] * w[e] * dinv[di] * x[si]);
    }
}
__global__ void g_kernel(const float* __restrict__ s, const float* __restrict__ dinv,
                         const float* __restrict__ x, const float* __restrict__ W1,
                         const float* __restrict__ b1, const float* __restrict__ W2,
                         float2* __restrict__ g, int N) {
    int n = blockIdx.x * blockDim.x + threadIdx.x;
    if (n < N) {
        float dv = dinv[n];
        float sv = s[n] + dv * dv * x[n];
        float g0 = 0.0f, g1 = 0.0f;
#pragma unroll
        for (int f = 0; f < 16; ++f) {
            float h = fmaxf(sv * W1[f] + b1[f], 0.0f);
            g0 += h * W2[2 * f + 0];
            g1 += h * W2[2 * f + 1];
        }
        g[n] = make_float2(g0, g1);
    }
}
__global__ void agg2_kernel(const int* __restrict__ src, const int* __restrict__ dst,
                            const float* __restrict__ w, const float* __restrict__ dinv,
                            const float2* __restrict__ g, float* __restrict__ agg, int E) {
    int e = blockIdx.x * blockDim.x + threadIdx.x;
    if (e < E) {
        int si = src[e], di = dst[e];
        float norm = dinv[si] * w[e] * dinv[di];
        float2 gv = g[si];
        atomicAdd(&agg[2 * di + 0], norm * gv.x);
        atomicAdd(&agg[2 * di + 1], norm * gv.y);
    }
}
__global__ void out_kernel(float* __restrict__ out, const float* __restrict__ dinv,
                           const float2* __restrict__ g, const float* __restrict__ b2, int N) {
    int n = blockIdx.x * blockDim.x + threadIdx.x;
    if (n < N) {
        float dv2 = dinv[n] * dinv[n];
        float2 gv = g[n];
        float a0 = out[2 * n + 0] + dv2 * gv.x + b2[0];
        float a1 = out[2 * n + 1] + dv2 * gv.y + b2[1];
        float m = fmaxf(a0, a1);
        float lse = m + logf(expf(a0 - m) + expf(a1 - m));
        out[2 * n + 0] = a0 - lse;
        out[2 * n + 1] = a1 - lse;
    }
}

// ======================= launch =======================

extern "C" void kernel_launch(void* const* d_in, const int* in_sizes, int n_in,
                              void* d_out, int out_size, void* d_ws, size_t ws_size,
                              hipStream_t stream) {
    const float* x  = (const float*)d_in[0];
    const int*   ei = (const int*)d_in[1];     // [2, E] delivered as int32
    const float* w  = (const float*)d_in[2];
    const float* W1 = (const float*)d_in[3];
    const float* b1 = (const float*)d_in[4];
    const float* W2 = (const float*)d_in[5];
    const float* b2 = (const float*)d_in[6];
    float* out = (float*)d_out;

    const int N = in_sizes[0];
    const int E = in_sizes[2];
    const int* src = ei;
    const int* dst = ei + E;

    const int nb = (N + CHUNK - 1) / CHUNK;    // 13
    const int nT = (E + EPT - 1) / EPT;        // 782

    // ws layout: payload | rowOff | partial | dinv | xd | gd
    size_t off = 0;
    size_t payload_off = off;  off += (size_t)nT * EPT * 8;
    size_t rowoff_off  = off;  off += (size_t)nT * (nb + 1) * 4;
    off = (off + 7) & ~(size_t)7;
    size_t partial_off = off;  off += (size_t)nb * K * CHUNK * 4;
    size_t dinv_off    = off;  off += (size_t)N * 4;
    size_t xd_off      = off;  off += (size_t)N * 4;
    size_t gd_off      = off;  off += (size_t)N * 4;
    const size_t required = off;

    if (nb <= NBMAX && N <= 131072 && ws_size >= required) {
        char* wsb = (char*)d_ws;
        unsigned long long* payload = (unsigned long long*)(wsb + payload_off);
        unsigned int* rowOff = (unsigned int*)(wsb + rowoff_off);
        float* partial = (float*)(wsb + partial_off);
        float* dinv = (float*)(wsb + dinv_off);
        float* xd   = (float*)(wsb + xd_off);
        float* gd   = (float*)(wsb + gd_off);

        const int gridA = nb * K;                  // 780
        const int gridM = (N + BSM - 1) / BSM;     // 391

        place_kernel    <<<nT,    BS_P, 0, stream>>>(src, dst, w, rowOff, payload, E, nb);
        deg_part_kernel <<<gridA, BSA,  0, stream>>>(payload, rowOff, partial, nb, nT);
        deg_merge_kernel<<<gridM, BSM,  0, stream>>>(partial, x, dinv, xd, N);
        s_part_kernel   <<<gridA, BSA,  0, stream>>>(payload, rowOff, xd, partial, nb, nT);
        s_merge_kernel  <<<gridM, BSM,  0, stream>>>(partial, dinv, xd, W1, b1, W2, gd, N);
        d_part_kernel   <<<gridA, BSA,  0, stream>>>(payload, rowOff, gd, partial, nb, nT);
        d_merge_kernel  <<<gridM, BSM,  0, stream>>>(partial, dinv, gd, b2, out, N);
    } else {
        // R3 fallback: global-atomic path (needs 4N floats of ws)
        float*  ws   = (float*)d_ws;
        float*  dinv = ws;
        float*  s    = ws + (size_t)N;
        float2* g    = (float2*)(ws + (size_t)2 * N);
        const int gridE  = (E + BLOCK - 1) / BLOCK;
        const int gridN  = (N + BLOCK - 1) / BLOCK;
        const int gridN2 = (2 * N + BLOCK - 1) / BLOCK;
        zero_kernel<<<gridN2, BLOCK, 0, stream>>>(ws, out, 2 * N);
        deg_kernel <<<gridE,  BLOCK, 0, stream>>>(dst, w, dinv, E);
        dinv_kernel<<<gridN,  BLOCK, 0, stream>>>(dinv, N);
        s_kernel   <<<gridE,  BLOCK, 0, stream>>>(src, dst, w, dinv, x, s, E);
        g_kernel   <<<gridN,  BLOCK, 0, stream>>>(s, dinv, x, W1, b1, W2, g, N);
        agg2_kernel<<<gridE,  BLOCK, 0, stream>>>(src, dst, w, dinv, g, out, E);
        out_kernel <<<gridN,  BLOCK, 0, stream>>>(out, dinv, g, b2, N);
    }
}